// Round 6
// baseline (110.321 us; speedup 1.0000x reference)
//
#include <hip/hip_runtime.h>
#include <hip/hip_bf16.h>
#include <cfloat>
#include <math.h>

#define BB 4
#define NR 180
#define CC 512
#define HH 48
#define WW 48
#define FF (CC*4)      // 2048
#define OO 64
#define EPSV 1e-5f
#define TW_LEVEL ((size_t)BB*HH*WW*CC)   // ushorts per table level = 4,718,592

// ---- ws layout ----
// featB : BB*HW*CC ushort (MAPPED u16 domain)          9.44 MB
// W1T4  : [512][64][4] float (W1T4[k>>2][o][k&3]=W1[o][k])  0.5 MB
// Tw    : 2 levels x [BB][HH][WW][CC] ushort (MAPPED)  18.87 MB
//         level 0 = width-4 col-max [x,min(x+4,W)); level 1 = width-8
//
// Pool segments have identical length len=ceil(wsz/2) <= 24; levels
// {L0(featB), w4, w8} + <=3 lookups cover all cases (R2/R3-verified logic).
//
// R4 lesson: no grid-wide spin barriers (160us). R6: k_tab merged INTO the
// transpose kernel (row-aligned blocks build tables in-LDS) -> 2 launches.

typedef unsigned short us2 __attribute__((ext_vector_type(2)));

__device__ __forceinline__ unsigned pmax(unsigned a, unsigned b) {
    return __builtin_bit_cast(unsigned, __builtin_elementwise_max(
        __builtin_bit_cast(us2, a), __builtin_bit_cast(us2, b)));
}
__device__ __forceinline__ uint4 pmax4(uint4 a, uint4 b) {
    return make_uint4(pmax(a.x,b.x), pmax(a.y,b.y), pmax(a.z,b.z), pmax(a.w,b.w));
}
__device__ __forceinline__ unsigned mapb(float f) {      // float -> mapped u16
    unsigned fu = __float_as_uint(f);
    unsigned u = fu >> 16;
    return (fu >> 31) ? (~u & 0xFFFFu) : (u | 0x8000u);
}
__device__ __forceinline__ void unmap2(unsigned m, float& lo, float& hi) {
    unsigned t = ((~m) >> 15) & 0x00010001u;             // 1 where orig negative
    unsigned u = m ^ (0x80008000u ^ (t * 0x7FFFu));      // per-lane: ^0x8000 / ^0xFFFF
    lo = __uint_as_float(u << 16);
    hi = __uint_as_float(u & 0xffff0000u);
}
__device__ __forceinline__ unsigned duphi(unsigned a) {  // (hi,hi)
    return (a >> 16) | (a & 0xFFFF0000u);
}

// ---------------- Kernel 1: transpose + map + table build (merged) ----------
// blocks 0..1535: (b, y, c0-slice of 64 ch), row-aligned. LDS x-packed u16
// doubling passes build w2 -> w4 -> w8; writes featB(L0), Tw[0](w4), Tw[1](w8)
// transposed to [s][c]. blocks 1536..1663: W1 transpose (verbatim).
__global__ __launch_bounds__(256) void k_prepab(const float* __restrict__ feat,
                                                const float* __restrict__ W1,
                                                ushort* __restrict__ featB,
                                                float* __restrict__ W1T4,
                                                ushort* __restrict__ Tw) {
    __shared__ unsigned Mx[64][26];   // x-packed u16: row = 48 x + 4 pad
    __shared__ unsigned Px[64][26];   // w2
    __shared__ unsigned Qx[64][26];   // w4
    int bid = blockIdx.x;
    int t = threadIdx.x;

    if (bid >= 1536) {                // ---- W1 transpose path ----
        float (*tile)[33] = (float(*)[33])&Mx[0][0];   // 4224 B < sizeof(Mx)
        int kt = bid - 1536;          // 0..127
        int k0 = (kt >> 1) * 32, o0 = (kt & 1) * 32;
        int tx = t & 31, ty = t >> 5;
        #pragma unroll
        for (int k = 0; k < 4; k++) {
            int row = ty + k * 8;
            tile[row][tx] = W1[(size_t)(o0 + row) * FF + (k0 + tx)];
        }
        __syncthreads();
        #pragma unroll
        for (int k = 0; k < 4; k++) {
            int row = ty + k * 8;
            int kk = k0 + row;
            int o  = o0 + tx;
            W1T4[(size_t)(kk >> 2) * 256 + o * 4 + (kk & 3)] = tile[tx][row];
        }
        return;
    }

    int b   = bid >> 7;               // /384 ... 384 = 48*8; do exact: b = bid/384
    b = bid / 384;
    int rem = bid - b * 384;
    int y   = rem >> 3;
    int c0  = (rem & 7) << 6;
    const float* src = feat + ((size_t)(b * CC + c0) * HH + y) * WW;
    size_t srow = ((size_t)b * HH + y) * WW;     // s base

    // ---- P0: load f32 row-slice, map, pack along x ----
    #pragma unroll
    for (int i = 0; i < 3; i++) {
        int u  = t + (i << 8);        // 0..767
        int cc = u / 12;
        int xq = u - cc * 12;
        float4 v = *(const float4*)(src + (size_t)cc * (HH * WW) + (xq << 2));
        unsigned m01 = mapb(v.x) | (mapb(v.y) << 16);
        unsigned m23 = mapb(v.z) | (mapb(v.w) << 16);
        *(uint2*)&Mx[cc][xq << 1] = make_uint2(m01, m23);
    }
    __syncthreads();

    // ---- P1: Px = width-2 col-max; W0: write featB (L0, transposed) ----
    #pragma unroll
    for (int i = 0; i < 6; i++) {
        int u  = t + (i << 8);        // 0..1535
        int ch = u / 24;
        int xu = u - ch * 24;
        unsigned A = Mx[ch][xu];
        unsigned B = Mx[ch][min(xu + 1, 23)];
        unsigned Be = (xu < 23) ? B : (A >> 16);
        unsigned C = (A >> 16) | (Be << 16);   // (m[x+1], m[x+2]) clamped
        Px[ch][xu] = pmax(A, C);
    }
    {
        const ushort* M16 = (const ushort*)&Mx[0][0];   // row stride 52 u16
        #pragma unroll
        for (int i = 0; i < 3; i++) {
            int u = t + (i << 8);     // 0..767
            int x = u >> 4;
            int q = u & 15;
            int e = (q << 2) * 52 + x;
            unsigned h0 = M16[e], h1 = M16[e + 52], h2 = M16[e + 104], h3 = M16[e + 156];
            *(uint2*)(featB + (srow + x) * CC + c0 + (q << 2)) =
                make_uint2(h0 | (h1 << 16), h2 | (h3 << 16));
        }
    }
    __syncthreads();

    // ---- P2: Qx = width-4 (from Px, +2x = +1 uint) ----
    #pragma unroll
    for (int i = 0; i < 6; i++) {
        int u  = t + (i << 8);
        int ch = u / 24;
        int xu = u - ch * 24;
        unsigned A = Px[ch][xu];
        unsigned B = Px[ch][min(xu + 1, 23)];
        unsigned S = (xu < 23) ? B : duphi(B);
        Qx[ch][xu] = pmax(A, S);
    }
    __syncthreads();

    // ---- W2: write Tw[0] (w4); P3: L3 = width-8 into Mx (Mx dead) ----
    #pragma unroll
    for (int i = 0; i < 6; i++) {
        int u  = t + (i << 8);
        int ch = u / 24;
        int xu = u - ch * 24;
        unsigned A = Qx[ch][xu];
        unsigned B = Qx[ch][min(xu + 2, 23)];
        unsigned S = (xu < 22) ? B : duphi(Qx[ch][23]);
        Mx[ch][xu] = pmax(A, S);
    }
    {
        const ushort* Q16 = (const ushort*)&Qx[0][0];
        #pragma unroll
        for (int i = 0; i < 3; i++) {
            int u = t + (i << 8);
            int x = u >> 4;
            int q = u & 15;
            int e = (q << 2) * 52 + x;
            unsigned h0 = Q16[e], h1 = Q16[e + 52], h2 = Q16[e + 104], h3 = Q16[e + 156];
            *(uint2*)(Tw + srow * CC + x * CC + c0 + (q << 2)) =
                make_uint2(h0 | (h1 << 16), h2 | (h3 << 16));
        }
    }
    __syncthreads();

    // ---- W3: write Tw[1] (w8) from Mx ----
    {
        const ushort* L16 = (const ushort*)&Mx[0][0];
        #pragma unroll
        for (int i = 0; i < 3; i++) {
            int u = t + (i << 8);
            int x = u >> 4;
            int q = u & 15;
            int e = (q << 2) * 52 + x;
            unsigned h0 = L16[e], h1 = L16[e + 52], h2 = L16[e + 104], h3 = L16[e + 156];
            *(uint2*)(Tw + TW_LEVEL + srow * CC + x * CC + c0 + (q << 2)) =
                make_uint2(h0 | (h1 << 16), h2 | (h3 << 16));
        }
    }
}

// ---------------- Kernel 2: fused ROI pool + BN1 + GEMM + BN2 (verbatim R3) -
__global__ __launch_bounds__(1024) void k_pg(const ushort* __restrict__ featB,
                                             const ushort* __restrict__ Tw,
                                             const float* __restrict__ rois,
                                             const float* __restrict__ W1T4,
                                             const float* __restrict__ bl1,
                                             const float* __restrict__ g1,
                                             const float* __restrict__ b1,
                                             const float* __restrict__ g2,
                                             const float* __restrict__ b2,
                                             float* __restrict__ out) {
    __shared__ unsigned lu[BB][4][16][65];    // 65 KB (pad 65: conflict-free)
    __shared__ float xs[BB][FF];              // 32 KB
    __shared__ float pd[16][BB][OO];          // 16 KB
    __shared__ float pw[16][OO];              // 4 KB
    __shared__ float part_s[16], part_q[16];
    __shared__ float sm2[4], sq2[4];

    int n = blockIdx.x;
    int tid = threadIdx.x;
    int b  = tid >> 8;                        // batch (wave-uniform)
    int g  = (tid >> 6) & 3;                  // rowgroup (wave-uniform)
    int c  = tid & 63;                        // channel-quad (uint4 = 8 ch)

    const float* roi = rois + ((size_t)b * NR + n) * 4;
    int r0 = (int)(roi[0] * 0.25f);
    int r1 = (int)(roi[1] * 0.25f);
    int r2 = (int)ceilf(roi[2] * 0.25f);
    int r3 = (int)ceilf(roi[3] * 0.25f);
    int hs  = r2 - r0 + 1;
    int wsz = r3 - r1 + 1;
    int eh0 = (hs + 1) >> 1, sh1 = hs >> 1;
    int sw1 = wsz >> 1;

    int len = (wsz + 1) >> 1;                 // == both segment lengths
    int ks  = (len >= 8) ? 3 : ((len >= 4) ? 2 : 0);
    int w   = 1 << ks;
    bool n3 = (len > 2 * w);                  // need 3rd (mid) lookup
    int xboff = (len >> 1) - (w >> 1);        // mid window offset from seg start
    int x0a = r1,        x0c = r1 + len - w,  x0b = r1 + xboff;
    int x1a = r1 + sw1,  x1c = r1 + wsz - w,  x1b = r1 + sw1 + xboff;
    const ushort* base = (ks == 0) ? featB : (Tw + (size_t)(ks - 2) * TW_LEVEL);

    const uint4 Z = make_uint4(0,0,0,0);      // 0 <= any mapped value
    uint4 q00 = Z, q01 = Z, q10 = Z, q11 = Z;
    for (int L = g; L < hs; L += 4) {
        size_t rowoff = (size_t)((b * HH + r0 + L) * WW) * CC;
        const uint4* p = (const uint4*)(base + rowoff) + c;
        uint4 cm0 = pmax4(p[(size_t)64 * x0a], p[(size_t)64 * x0c]);
        uint4 cm1 = pmax4(p[(size_t)64 * x1a], p[(size_t)64 * x1c]);
        if (n3) {
            cm0 = pmax4(cm0, p[(size_t)64 * x0b]);
            cm1 = pmax4(cm1, p[(size_t)64 * x1b]);
        }
        if (L <  eh0) { q00 = pmax4(q00, cm0); q01 = pmax4(q01, cm1); }
        if (L >= sh1) { q10 = pmax4(q10, cm0); q11 = pmax4(q11, cm1); }
    }

    {
        unsigned* L0 = &lu[b][g][0][c];       // j-stride = 65 uints
        unsigned a, p2;
        a = q00.x; p2 = q01.x;
        L0[ 0*65] = (a & 0xFFFFu) | (p2 << 16);           // ch0, oi0
        L0[ 2*65] = (a >> 16)     | (p2 & 0xFFFF0000u);   // ch1, oi0
        a = q10.x; p2 = q11.x;
        L0[ 1*65] = (a & 0xFFFFu) | (p2 << 16);           // ch0, oi1
        L0[ 3*65] = (a >> 16)     | (p2 & 0xFFFF0000u);   // ch1, oi1
        a = q00.y; p2 = q01.y;
        L0[ 4*65] = (a & 0xFFFFu) | (p2 << 16);
        L0[ 6*65] = (a >> 16)     | (p2 & 0xFFFF0000u);
        a = q10.y; p2 = q11.y;
        L0[ 5*65] = (a & 0xFFFFu) | (p2 << 16);
        L0[ 7*65] = (a >> 16)     | (p2 & 0xFFFF0000u);
        a = q00.z; p2 = q01.z;
        L0[ 8*65] = (a & 0xFFFFu) | (p2 << 16);
        L0[10*65] = (a >> 16)     | (p2 & 0xFFFF0000u);
        a = q10.z; p2 = q11.z;
        L0[ 9*65] = (a & 0xFFFFu) | (p2 << 16);
        L0[11*65] = (a >> 16)     | (p2 & 0xFFFF0000u);
        a = q00.w; p2 = q01.w;
        L0[12*65] = (a & 0xFFFFu) | (p2 << 16);
        L0[14*65] = (a >> 16)     | (p2 & 0xFFFF0000u);
        a = q10.w; p2 = q11.w;
        L0[13*65] = (a & 0xFFFFu) | (p2 << 16);
        L0[15*65] = (a >> 16)     | (p2 & 0xFFFF0000u);
    }
    __syncthreads();

    float s_acc = 0.f, q_acc = 0.f;
    int s  = tid & 255;
    int bb = tid >> 8;
    #pragma unroll
    for (int p = 0; p < 2; p++) {
        int fb = (p << 10) + (s << 2);
        int cc = fb >> 5;
        int j0 = (fb >> 1) & 15;              // even
        unsigned m0 = pmax(pmax(lu[bb][0][j0  ][cc], lu[bb][1][j0  ][cc]),
                           pmax(lu[bb][2][j0  ][cc], lu[bb][3][j0  ][cc]));
        unsigned m1 = pmax(pmax(lu[bb][0][j0+1][cc], lu[bb][1][j0+1][cc]),
                           pmax(lu[bb][2][j0+1][cc], lu[bb][3][j0+1][cc]));
        m0 = pmax(m0, 0x80008000u);           // ReLU: mapped(+0) = 0x8000
        m1 = pmax(m1, 0x80008000u);
        float v0, v1, v2, v3;
        unmap2(m0, v0, v1);
        unmap2(m1, v2, v3);
        *(float4*)&xs[bb][fb] = make_float4(v0, v1, v2, v3);
        s_acc += v0 + v1 + v2 + v3;
        q_acc += v0*v0 + v1*v1 + v2*v2 + v3*v3;
    }
    for (int off = 32; off; off >>= 1) {
        s_acc += __shfl_down(s_acc, off);
        q_acc += __shfl_down(q_acc, off);
    }
    if ((tid & 63) == 0) { part_s[tid >> 6] = s_acc; part_q[tid >> 6] = q_acc; }
    __syncthreads();
    float ts = 0.f, tq = 0.f;
    #pragma unroll
    for (int i = 0; i < 16; i++) { ts += part_s[i]; tq += part_q[i]; }
    const float inv1 = 1.f / (float)(BB * FF);
    float mean = ts * inv1;
    float var  = tq * inv1 - mean * mean;
    float a1n  = g1[n] * rsqrtf(var + EPSV);
    float c1n  = b1[n] - mean * a1n;

    int sc = tid >> 6;
    int o  = tid & 63;
    int k4a = sc << 5;
    float a0 = 0.f, a1 = 0.f, a2 = 0.f, a3 = 0.f, wsum = 0.f;
    #pragma unroll 4
    for (int k4 = k4a; k4 < k4a + 32; k4++) {
        float4 w4 = *(const float4*)(W1T4 + (size_t)k4 * 256 + o * 4);
        float4 x0 = *(const float4*)&xs[0][k4 << 2];
        float4 x1 = *(const float4*)&xs[1][k4 << 2];
        float4 x2 = *(const float4*)&xs[2][k4 << 2];
        float4 x3 = *(const float4*)&xs[3][k4 << 2];
        wsum += w4.x + w4.y + w4.z + w4.w;
        a0 += w4.x*x0.x + w4.y*x0.y + w4.z*x0.z + w4.w*x0.w;
        a1 += w4.x*x1.x + w4.y*x1.y + w4.z*x1.z + w4.w*x1.w;
        a2 += w4.x*x2.x + w4.y*x2.y + w4.z*x2.z + w4.w*x2.w;
        a3 += w4.x*x3.x + w4.y*x3.y + w4.z*x3.z + w4.w*x3.w;
    }
    pd[sc][0][o] = a0; pd[sc][1][o] = a1; pd[sc][2][o] = a2; pd[sc][3][o] = a3;
    pw[sc][o] = wsum;
    __syncthreads();

    float y = 0.f;
    int bo = tid >> 6;
    if (tid < 256) {
        float dot = 0.f, wsm = 0.f;
        #pragma unroll
        for (int ss = 0; ss < 16; ss++) { dot += pd[ss][bo][o]; wsm += pw[ss][o]; }
        y = a1n * dot + c1n * wsm + bl1[o];
        float rs = y, rq = y * y;
        for (int off = 32; off; off >>= 1) {
            rs += __shfl_down(rs, off);
            rq += __shfl_down(rq, off);
        }
        if (o == 0) { sm2[bo] = rs; sq2[bo] = rq; }
    }
    __syncthreads();
    if (tid < 256) {
        float sm  = sm2[0] + sm2[1] + sm2[2] + sm2[3];
        float sqm = sq2[0] + sq2[1] + sq2[2] + sq2[3];
        const float inv2 = 1.f / 256.f;
        float mean2 = sm * inv2;
        float var2  = sqm * inv2 - mean2 * mean2;
        float r2s = rsqrtf(var2 + EPSV);
        out[((size_t)bo * NR + n) * OO + o] = (y - mean2) * r2s * g2[n] + b2[n];
    }
}

extern "C" void kernel_launch(void* const* d_in, const int* in_sizes, int n_in,
                              void* d_out, int out_size, void* d_ws, size_t ws_size,
                              hipStream_t stream) {
    const float* feat = (const float*)d_in[0];
    const float* rois = (const float*)d_in[1];
    const float* g1   = (const float*)d_in[2];
    const float* b1   = (const float*)d_in[3];
    const float* W1   = (const float*)d_in[4];
    const float* bl1  = (const float*)d_in[5];
    const float* g2   = (const float*)d_in[6];
    const float* b2   = (const float*)d_in[7];
    float* out = (float*)d_out;

    ushort* featB = (ushort*)d_ws;                        // mapped u16
    float*  W1T4  = (float*)(featB + TW_LEVEL);
    ushort* Tw    = (ushort*)(W1T4 + (size_t)OO*FF);      // 18.87 MB (2 levels)

    k_prepab<<<dim3(1664), 256, 0, stream>>>(feat, W1, featB, W1T4, Tw);
    k_pg<<<NR, 1024, 0, stream>>>(featB, Tw, rois, W1T4, bl1, g1, b1, g2, b2, out);
}